// Round 8
// baseline (146.683 us; speedup 1.0000x reference)
//
#include <hip/hip_runtime.h>
#include <hip/hip_bf16.h>

// Problem constants (B=4, S=1024, d=512, H=8, hd=64)
#define BB 4
#define SS 1024
#define DD 512
#define HH 8
#define HD 64

typedef __attribute__((ext_vector_type(8))) short bf16x8;
typedef __attribute__((ext_vector_type(4))) float f32x4;

// fp32 -> bf16 round-to-nearest-even (finite inputs)
static __device__ __forceinline__ unsigned short f2b(float f) {
  union { float f; unsigned int u; } c; c.f = f;
  return (unsigned short)((c.u + 0x7fffu + ((c.u >> 16) & 1u)) >> 16);
}

// ---------------------------------------------------------------------------
// Fused prep (one dispatch):
//  blocks [0,1024):    x fp32 -> bf16           (2M elems)
//  blocks [1024,1280): in_proj_w q|k rows -> bf16 (512K)
//  blocks [1280,1408): out_w -> bf16            (256K)
//  blocks [1408,3456): mask bit-pack: 8 fp32 -> 1 byte (4.19M -> 512 KB)
//  blocks [3456,3968): V [B,S,H,hd] fp32 -> Vt [B,H,hd,S] bf16 (transpose)
// ---------------------------------------------------------------------------
__global__ __launch_bounds__(256) void prep(
    const float* __restrict__ x, const float* __restrict__ W1,
    const float* __restrict__ Wo, const float* __restrict__ Mmask,
    const float* __restrict__ V, unsigned short* __restrict__ xb,
    unsigned short* __restrict__ W1b, unsigned short* __restrict__ Wob,
    unsigned char* __restrict__ Mpack, unsigned short* __restrict__ Vt) {
  __shared__ float Ls[64][65];
  const int bid = blockIdx.x;
  const int tid = threadIdx.x;

  if (bid < 1408) {  // bf16 conversions, 8 elems/thread
    const float* src; unsigned short* dst; size_t off;
    if (bid < 1024) { src = x;  dst = xb;  off = ((size_t)bid * 256 + tid) * 8; }
    else if (bid < 1280) { src = W1; dst = W1b; off = ((size_t)(bid - 1024) * 256 + tid) * 8; }
    else { src = Wo; dst = Wob; off = ((size_t)(bid - 1280) * 256 + tid) * 8; }
    const float4 a = *(const float4*)(src + off);
    const float4 b = *(const float4*)(src + off + 4);
    union { unsigned short s[8]; uint4 v; } o;
    o.s[0] = f2b(a.x); o.s[1] = f2b(a.y); o.s[2] = f2b(a.z); o.s[3] = f2b(a.w);
    o.s[4] = f2b(b.x); o.s[5] = f2b(b.y); o.s[6] = f2b(b.z); o.s[7] = f2b(b.w);
    *(uint4*)(dst + off) = o.v;
  } else if (bid < 3456) {  // mask bit-pack: thread g -> byte g (8 fp32 bits)
    const size_t g = (size_t)(bid - 1408) * 256 + tid;
    const float4 a = *(const float4*)(Mmask + g * 8);
    const float4 b = *(const float4*)(Mmask + g * 8 + 4);
    unsigned v = 0;
    v |= (a.x > 0.5f) ? 1u : 0u;   v |= (a.y > 0.5f) ? 2u : 0u;
    v |= (a.z > 0.5f) ? 4u : 0u;   v |= (a.w > 0.5f) ? 8u : 0u;
    v |= (b.x > 0.5f) ? 16u : 0u;  v |= (b.y > 0.5f) ? 32u : 0u;
    v |= (b.z > 0.5f) ? 64u : 0u;  v |= (b.w > 0.5f) ? 128u : 0u;
    Mpack[g] = (unsigned char)v;
  } else {  // V transpose tile
    const int id = bid - 3456;
    const int s0 = (id & 15) * 64, h = (id >> 4) & 7, b = id >> 7;
    {
      const int r = tid >> 2, cs = (tid & 3) * 16;
      const float* src = V + ((size_t)((b * SS + s0 + r) * HH) + h) * HD + cs;
#pragma unroll
      for (int j = 0; j < 4; j++) {
        const float4 v = *(const float4*)(src + j * 4);
        Ls[r][cs + j * 4 + 0] = v.x; Ls[r][cs + j * 4 + 1] = v.y;
        Ls[r][cs + j * 4 + 2] = v.z; Ls[r][cs + j * 4 + 3] = v.w;
      }
    }
    __syncthreads();
    {
      const int d = tid >> 2, ss = (tid & 3) * 16;
      union { unsigned short s[16]; uint4 v[2]; } o;
#pragma unroll
      for (int j = 0; j < 16; j++) o.s[j] = f2b(Ls[ss + j][d]);
      unsigned short* dst =
          Vt + ((size_t)((b * HH + h) * HD + d)) * SS + s0 + ss;
      *(uint4*)dst = o.v[0];
      *(uint4*)(dst + 8) = o.v[1];
    }
  }
}

// ---------------------------------------------------------------------------
// GEMM1: qkb[4096,1024](bf16) = xb(bf16) @ W1b(bf16)^T + bias
// 64x64 tile, BK=32, 256 thr -> 1024 blocks (occupancy for latency-bound).
// ---------------------------------------------------------------------------
__global__ __launch_bounds__(256) void gemm_qk(
    const unsigned short* __restrict__ xb, const unsigned short* __restrict__ W1b,
    const float* __restrict__ bias, unsigned short* __restrict__ qkb) {
  __shared__ unsigned short As[64][40];
  __shared__ unsigned short Bs[64][40];
  const int tid = threadIdx.x;
  const int lane = tid & 63, wave = tid >> 6;
  const int l16 = lane & 15, quad = lane >> 4;
  const int row0 = blockIdx.y * 64, col0 = blockIdx.x * 64;

  f32x4 acc[4];
#pragma unroll
  for (int j = 0; j < 4; j++) acc[j] = (f32x4){0.f, 0.f, 0.f, 0.f};

  for (int k0 = 0; k0 < DD; k0 += 32) {
    __syncthreads();
    {
      const int r = tid >> 2, cs = (tid & 3) * 8;
      *(uint4*)&As[r][cs] =
          *(const uint4*)(xb + (size_t)(row0 + r) * DD + k0 + cs);
      *(uint4*)&Bs[r][cs] =
          *(const uint4*)(W1b + (size_t)(col0 + r) * DD + k0 + cs);
    }
    __syncthreads();

    const bf16x8 a0 = *(const bf16x8*)&As[wave * 16 + l16][quad * 8];
#pragma unroll
    for (int nt = 0; nt < 4; nt++) {
      const bf16x8 bb = *(const bf16x8*)&Bs[nt * 16 + l16][quad * 8];
      acc[nt] = __builtin_amdgcn_mfma_f32_16x16x32_bf16(a0, bb, acc[nt], 0, 0, 0);
    }
  }

#pragma unroll
  for (int nt = 0; nt < 4; nt++) {
    const int col = col0 + nt * 16 + l16;
    const float bv = bias[col];
#pragma unroll
    for (int reg = 0; reg < 4; reg++) {
      const int row = row0 + wave * 16 + quad * 4 + reg;
      qkb[(size_t)row * 1024 + col] = f2b(acc[nt][reg] + bv);
    }
  }
}

// ---------------------------------------------------------------------------
// GEMM3: out[4096,512](fp32) = attnb(bf16) @ Wob(bf16)^T + out_b
// ---------------------------------------------------------------------------
__global__ __launch_bounds__(256) void gemm_out(
    const unsigned short* __restrict__ Ab, const unsigned short* __restrict__ Wob,
    const float* __restrict__ bias, float* __restrict__ out) {
  __shared__ unsigned short As[64][40];
  __shared__ unsigned short Bs[64][40];
  const int tid = threadIdx.x;
  const int lane = tid & 63, wave = tid >> 6;
  const int l16 = lane & 15, quad = lane >> 4;
  const int row0 = blockIdx.y * 64, col0 = blockIdx.x * 64;

  f32x4 acc[4];
#pragma unroll
  for (int j = 0; j < 4; j++) acc[j] = (f32x4){0.f, 0.f, 0.f, 0.f};

  for (int k0 = 0; k0 < DD; k0 += 32) {
    __syncthreads();
    {
      const int r = tid >> 2, cs = (tid & 3) * 8;
      *(uint4*)&As[r][cs] =
          *(const uint4*)(Ab + (size_t)(row0 + r) * DD + k0 + cs);
      *(uint4*)&Bs[r][cs] =
          *(const uint4*)(Wob + (size_t)(col0 + r) * DD + k0 + cs);
    }
    __syncthreads();

    const bf16x8 a0 = *(const bf16x8*)&As[wave * 16 + l16][quad * 8];
#pragma unroll
    for (int nt = 0; nt < 4; nt++) {
      const bf16x8 bb = *(const bf16x8*)&Bs[nt * 16 + l16][quad * 8];
      acc[nt] = __builtin_amdgcn_mfma_f32_16x16x32_bf16(a0, bb, acc[nt], 0, 0, 0);
    }
  }

#pragma unroll
  for (int nt = 0; nt < 4; nt++) {
    const int col = col0 + nt * 16 + l16;
    const float bv = bias[col];
#pragma unroll
    for (int reg = 0; reg < 4; reg++) {
      const int row = row0 + wave * 16 + quad * 4 + reg;
      out[(size_t)row * DD + col] = acc[nt][reg] + bv;
    }
  }
}

// ---------------------------------------------------------------------------
// MFMA flash attention, intra-block split-k (no global partials).
// Block = (64-q tile, h, b), 512 threads = 8 waves: wave = (qg = wave&3,
// kh = wave>>2). Wave handles 16 q rows (qg) and 8 of 16 k-tiles (kh).
// Both K/V halves staged per iteration. Cross-wave combine via LDS (the P
// scratch region reinterpreted as fp32), final bf16 attnb written directly.
//  - S^T = mfma(A=K_frag, B=Q_frag): lane holds P^T[s=quad*4+reg][q=l16].
//  - bit-packed mask preloaded to registers (64 B / lane / half).
//  - no max shift (|s| bounded ~1.6), no eps*Z term (rel ~2e-8).
// ---------------------------------------------------------------------------
__global__ __launch_bounds__(512) void flash_attn(
    const unsigned short* __restrict__ qkb, const unsigned short* __restrict__ Vt,
    const unsigned char* __restrict__ Mpack, unsigned short* __restrict__ attnb) {
  __shared__ unsigned short Qs[64][72];      // 9.2 KB
  __shared__ unsigned short Ks[2][64][72];   // 18.4 KB
  __shared__ unsigned short Vs[2][64][72];   // 18.4 KB  [half][d][s]
  __shared__ unsigned short Ps[8][16][72];   // 18.4 KB; epilogue: fp32 scratch

  const int tid = threadIdx.x;
  const int lane = tid & 63, wave = tid >> 6;
  const int l16 = lane & 15, quad = lane >> 4;
  const int qg = wave & 3, kh = wave >> 2;
  const int q0 = blockIdx.x * 64;
  const int h = blockIdx.y;
  const int b = blockIdx.z;

  {  // stage Q tile: 64x64 bf16, 1 uint4/thread
    const int r = tid >> 3, cs = (tid & 7) * 8;
    *(uint4*)&Qs[r][cs] =
        *(const uint4*)(qkb + (size_t)(b * SS + q0 + r) * 1024 + h * HD + cs);
  }

  // preload this lane's mask bits for its half (q = q0+qg*16+l16): 64 B
  union { uint4 v[4]; unsigned w[16]; } mu;
  {
    const uint4* mp = (const uint4*)(Mpack +
        (size_t)(b * SS + q0 + qg * 16 + l16) * 128 + kh * 64);
    mu.v[0] = mp[0]; mu.v[1] = mp[1]; mu.v[2] = mp[2]; mu.v[3] = mp[3];
  }

  __syncthreads();
  const bf16x8 bQ0 = *(const bf16x8*)&Qs[qg * 16 + l16][quad * 8];
  const bf16x8 bQ1 = *(const bf16x8*)&Qs[qg * 16 + l16][32 + quad * 8];

  float Smp = 0.f;
  f32x4 O[4];
#pragma unroll
  for (int i = 0; i < 4; i++) O[i] = (f32x4){0.f, 0.f, 0.f, 0.f};

  const unsigned short* kbase = qkb + (size_t)(b * SS) * 1024 + DD + h * HD;
  const unsigned short* vbase = Vt + (size_t)((b * HH + h) * HD) * SS;

#pragma unroll 2
  for (int i = 0; i < 8; i++) {
    const unsigned mlo = mu.w[2 * i], mhi = mu.w[2 * i + 1];

    __syncthreads();
    {  // stage K/V both halves: 4 tiles x 1 uint4/thread
      const int r = tid >> 3, cs = (tid & 7) * 8;
      *(uint4*)&Ks[0][r][cs] =
          *(const uint4*)(kbase + (size_t)(i * 64 + r) * 1024 + cs);
      *(uint4*)&Ks[1][r][cs] =
          *(const uint4*)(kbase + (size_t)(512 + i * 64 + r) * 1024 + cs);
      *(uint4*)&Vs[0][r][cs] =
          *(const uint4*)(vbase + (size_t)r * SS + i * 64 + cs);
      *(uint4*)&Vs[1][r][cs] =
          *(const uint4*)(vbase + (size_t)r * SS + 512 + i * 64 + cs);
    }
    __syncthreads();

    // ---- S^T tiles: D[s=quad*4+reg][q=l16]; exp, mask-bit select, P pack ----
#pragma unroll
    for (int t = 0; t < 4; t++) {
      const bf16x8 aK0 = *(const bf16x8*)&Ks[kh][t * 16 + l16][quad * 8];
      const bf16x8 aK1 = *(const bf16x8*)&Ks[kh][t * 16 + l16][32 + quad * 8];
      f32x4 a = (f32x4){0.f, 0.f, 0.f, 0.f};
      a = __builtin_amdgcn_mfma_f32_16x16x32_bf16(aK0, bQ0, a, 0, 0, 0);
      a = __builtin_amdgcn_mfma_f32_16x16x32_bf16(aK1, bQ1, a, 0, 0, 0);
      const unsigned nib =
          ((t < 2 ? mlo : mhi) >> ((t & 1) * 16 + quad * 4)) & 0xFu;
      float e0 = __expf(a[0] * 0.125f); e0 = (nib & 1u) ? e0 : 0.f;
      float e1 = __expf(a[1] * 0.125f); e1 = (nib & 2u) ? e1 : 0.f;
      float e2 = __expf(a[2] * 0.125f); e2 = (nib & 4u) ? e2 : 0.f;
      float e3 = __expf(a[3] * 0.125f); e3 = (nib & 8u) ? e3 : 0.f;
      Smp += (e0 + e1) + (e2 + e3);
      uint2 w;
      w.x = (unsigned)f2b(e0) | ((unsigned)f2b(e1) << 16);
      w.y = (unsigned)f2b(e2) | ((unsigned)f2b(e3) << 16);
      *(uint2*)&Ps[wave][l16][t * 16 + quad * 4] = w;  // ds_write_b64
    }

    // ---- O += P @ V (wave-private P; in-wave DS ordering suffices) ----
    const bf16x8 aP0 = *(const bf16x8*)&Ps[wave][l16][quad * 8];
    const bf16x8 aP1 = *(const bf16x8*)&Ps[wave][l16][32 + quad * 8];
#pragma unroll
    for (int dt = 0; dt < 4; dt++) {
      const bf16x8 bV0 = *(const bf16x8*)&Vs[kh][dt * 16 + l16][quad * 8];
      const bf16x8 bV1 = *(const bf16x8*)&Vs[kh][dt * 16 + l16][32 + quad * 8];
      O[dt] = __builtin_amdgcn_mfma_f32_16x16x32_bf16(aP0, bV0, O[dt], 0, 0, 0);
      O[dt] = __builtin_amdgcn_mfma_f32_16x16x32_bf16(aP1, bV1, O[dt], 0, 0, 0);
    }
  }

  // ---- epilogue: combine the two k-halves in LDS, scale, store bf16 ----
  // Sm: reduce over quads -> every lane holds Sm for q = l16 (its half).
  Smp += __shfl_xor(Smp, 16);
  Smp += __shfl_xor(Smp, 32);

  __syncthreads();  // all PV reads of Ps done; safe to reuse as fp32 scratch
  float* scratch = (float*)&Ps[0][0][0];  // 4608 floats
  float* Obuf = scratch;                  // [qg 4][q 16][d 64] = 4096
  float* SmT = scratch + 4096;            // [kh 2][qg 4][q 16] = 128

  if (lane < 16) SmT[kh * 64 + qg * 16 + lane] = Smp;
  if (kh == 1) {
#pragma unroll
    for (int reg = 0; reg < 4; reg++)
#pragma unroll
      for (int dt = 0; dt < 4; dt++)
        Obuf[qg * 1024 + (quad * 4 + reg) * 64 + dt * 16 + l16] = O[dt][reg];
  }
  __syncthreads();

  if (kh == 0) {
    float invr[4];
#pragma unroll
    for (int reg = 0; reg < 4; reg++) {
      const int qi = qg * 16 + quad * 4 + reg;
      const float s = SmT[qi] + SmT[64 + qi];
      invr[reg] = 1.0f / (s + 1e-12f);
    }
#pragma unroll
    for (int reg = 0; reg < 4; reg++) {
      const size_t row = (size_t)(b * SS + q0 + qg * 16 + quad * 4 + reg);
#pragma unroll
      for (int dt = 0; dt < 4; dt++) {
        const float o =
            (O[dt][reg] + Obuf[qg * 1024 + (quad * 4 + reg) * 64 + dt * 16 + l16]) *
            invr[reg];
        attnb[row * DD + h * HD + dt * 16 + l16] = f2b(o);
      }
    }
  }
}

// ---------------------------------------------------------------------------
extern "C" void kernel_launch(void* const* d_in, const int* in_sizes, int n_in,
                              void* d_out, int out_size, void* d_ws,
                              size_t ws_size, hipStream_t stream) {
  const float* x = (const float*)d_in[0];          // [4,1024,512]
  const float* V = (const float*)d_in[1];          // [4,1024,8,64]
  const float* Mmask = (const float*)d_in[2];      // [4,1024,1024]
  const float* in_proj_w = (const float*)d_in[3];  // [1536,512]
  const float* in_proj_b = (const float*)d_in[4];  // [1536]
  const float* out_w = (const float*)d_in[5];      // [512,512]
  const float* out_b = (const float*)d_in[6];      // [512]
  float* out = (float*)d_out;                      // [4,1024,512]

  unsigned char* ws = (unsigned char*)d_ws;
  unsigned short* qkb   = (unsigned short*)(ws);                     // 8 MB
  unsigned short* xb    = (unsigned short*)(ws + (8ull << 20));      // 4 MB
  unsigned short* W1b   = (unsigned short*)(ws + (12ull << 20));     // 1 MB
  unsigned short* Wob   = (unsigned short*)(ws + (13ull << 20));     // 0.5 MB
  unsigned short* Vt    = (unsigned short*)(ws + (14ull << 20));     // 4 MB
  unsigned short* attnb = (unsigned short*)(ws + (18ull << 20));     // 4 MB
  unsigned char*  Mpack = ws + (22ull << 20);                        // 512 KB

  prep<<<3968, 256, 0, stream>>>(x, in_proj_w, out_w, Mmask, V,
                                 xb, W1b, Wob, Mpack, Vt);
  gemm_qk<<<dim3(16, 64), 256, 0, stream>>>(xb, W1b, in_proj_b, qkb);
  flash_attn<<<dim3(SS / 64, HH, BB), 512, 0, stream>>>(qkb, Vt, Mpack, attnb);
  gemm_out<<<dim3(8, 64), 256, 0, stream>>>(attnb, Wob, out_b, out);
}